// Round 1
// baseline (3107.476 us; speedup 1.0000x reference)
//
#include <hip/hip_runtime.h>
#include <hip/hip_bf16.h>

#define POOLN 14
#define NBINS 196
#define CCH 512
#define MROIS 512
#define HIDD 1024
#define NCLS 81
#define KTOT 100352  // 512*196

typedef short short8 __attribute__((ext_vector_type(8)));
typedef __bf16 bf16x8 __attribute__((ext_vector_type(8)));
typedef float float4v __attribute__((ext_vector_type(4)));

__device__ __forceinline__ float4v mfma_bf16(bf16x8 a, bf16x8 b, float4v c) {
    return __builtin_amdgcn_mfma_f32_16x16x32_bf16(a, b, c, 0, 0, 0);
}

__device__ __forceinline__ unsigned short f2bf(float v) {
    __hip_bfloat16 h = __float2bfloat16(v);
    return __builtin_bit_cast(unsigned short, h);
}

// ---------------------------------------------------------------------------
// RoIAlign: one block = (box m, 256-channel half). Writes pooled[m][p][c] bf16.
// ---------------------------------------------------------------------------
__global__ void k_roi(const float* __restrict__ p2, const float* __restrict__ p3,
                      const float* __restrict__ p4, const float* __restrict__ p5,
                      const float* __restrict__ boxes, const int* __restrict__ bidx,
                      const int* __restrict__ imh, const int* __restrict__ imw,
                      unsigned short* __restrict__ pooled) {
    int m = blockIdx.x >> 1;
    int c = ((blockIdx.x & 1) << 8) + threadIdx.x;
    float b0 = boxes[m*4+0], b1 = boxes[m*4+1], b2 = boxes[m*4+2], b3 = boxes[m*4+3];
    int ih = imh[0], iw = imw[0];
    float alpha = (224.0f/800.0f) * (float)(ih < iw ? ih : iw);
    float bw = fabsf(b2-b0), bh = fabsf(b3-b1);
    float s = sqrtf(fmaxf(bw*bh, 1e-6f));
    float kf = floorf(4.0f + log2f(s/alpha)) - 2.0f;
    int lvl = (int)fminf(fmaxf(kf, 0.0f), 3.0f);
    const float* f = lvl==0 ? p2 : (lvl==1 ? p3 : (lvl==2 ? p4 : p5));
    int W = 200 >> lvl;
    float scale = 1.0f / (float)(4 << lvl);
    float x1s=b0*scale, y1s=b1*scale, x2s=b2*scale, y2s=b3*scale;
    int n = bidx[m];
    const float* fb = f + (size_t)(n*CCH + c) * (size_t)(W*W);
    unsigned short* outp = pooled + (size_t)m * NBINS * CCH + c;
    float Wm1 = (float)(W-1);
    for (int py = 0; py < POOLN; ++py) {
        float gy = ((float)py + 0.5f) / 14.0f;
        float ys = y1s + gy * (y2s - y1s);
        float y0f = floorf(ys);
        float ly = ys - y0f;
        int y0 = (int)fminf(fmaxf(y0f, 0.0f), Wm1);
        int y1 = (int)fminf(fmaxf(y0f+1.0f, 0.0f), Wm1);
        const float* r0 = fb + (size_t)(y0*W);
        const float* r1 = fb + (size_t)(y1*W);
        #pragma unroll
        for (int px = 0; px < POOLN; ++px) {
            float gx = ((float)px + 0.5f) / 14.0f;
            float xs = x1s + gx * (x2s - x1s);
            float x0f = floorf(xs);
            float lx = xs - x0f;
            int x0 = (int)fminf(fmaxf(x0f, 0.0f), Wm1);
            int x1 = (int)fminf(fmaxf(x0f+1.0f, 0.0f), Wm1);
            float v00 = r0[x0], v01 = r0[x1], v10 = r1[x0], v11 = r1[x1];
            float v = v00*(1.0f-ly)*(1.0f-lx) + v01*(1.0f-ly)*lx
                    + v10*ly*(1.0f-lx) + v11*ly*lx;
            outp[(size_t)(py*POOLN+px) * CCH] = f2bf(v);
        }
    }
}

// ---------------------------------------------------------------------------
// Pre-pack w_fc1 fp32 [k=c*196+p][n] -> bf16 packed [k'/8][n][8], k' = p*512+c
// ---------------------------------------------------------------------------
__global__ void k_pack_wfc1(const float* __restrict__ w, unsigned short* __restrict__ pk) {
    int g = blockIdx.x * 256 + threadIdx.x;   // < 12544*1024
    int n = g & 1023;
    int k8 = g >> 10;
    int kp = k8 << 3;
    int p  = kp >> 9;
    int cc = kp & 511;
    short8 hv;
    #pragma unroll
    for (int j = 0; j < 8; ++j) {
        float v = w[(size_t)((cc+j)*NBINS + p) * HIDD + n];
        hv[j] = (short)f2bf(v);
    }
    *(short8*)(pk + (size_t)g * 8) = hv;
}

// w_conv fp32 [oc][c][3][3] -> bf16 [tap][oc][c]
__global__ void k_pack_wconv(const float* __restrict__ w, unsigned short* __restrict__ wb) {
    int g = blockIdx.x * 256 + threadIdx.x;   // < 9*256*512
    int c  = g & 511;
    int oc = (g >> 9) & 255;
    int kk = g >> 17;
    wb[g] = f2bf(w[(size_t)(oc*512 + c)*9 + kk]);
}

// ---------------------------------------------------------------------------
// fc1 GEMM: [512,100352]x[100352,1024], BM=BN=128, BK=32, split-K=16 -> partials
// ---------------------------------------------------------------------------
__launch_bounds__(256)
__global__ void k_fc1(const unsigned short* __restrict__ A, const unsigned short* __restrict__ B,
                      float* __restrict__ part) {
    __shared__ unsigned short As[128*40];
    __shared__ unsigned short Bs[128*40];
    int t = threadIdx.x;
    int n0 = blockIdx.x * 128;
    int m0 = blockIdx.y * 128;
    int kz = blockIdx.z;
    int wave = t >> 6, ln = t & 63, ln15 = ln & 15, q = ln >> 4;
    int wr = (wave >> 1) * 64, wc = (wave & 1) * 64;
    float4v acc[4][4];
    #pragma unroll
    for (int i = 0; i < 4; ++i)
        #pragma unroll
        for (int j = 0; j < 4; ++j) acc[i][j] = (float4v){0.f,0.f,0.f,0.f};
    int kbase = kz * 6272;
    for (int it = 0; it < 196; ++it) {
        int k0 = kbase + it*32;
        __syncthreads();
        #pragma unroll
        for (int i = 0; i < 2; ++i) {
            int g = t + i*256;
            int row = g >> 2, seg = g & 3;
            short8 v = *(const short8*)(A + (size_t)(m0+row)*KTOT + k0 + seg*8);
            *(short8*)(&As[row*40 + seg*8]) = v;
        }
        #pragma unroll
        for (int i = 0; i < 2; ++i) {
            int g = t + i*256;
            int nl = g & 127, k8i = g >> 7;
            short8 v = *(const short8*)(B + ((size_t)((k0>>3) + k8i)*1024 + n0 + nl)*8);
            *(short8*)(&Bs[nl*40 + k8i*8]) = v;
        }
        __syncthreads();
        bf16x8 bfr[4];
        #pragma unroll
        for (int ct = 0; ct < 4; ++ct)
            bfr[ct] = *(const bf16x8*)(&Bs[(wc + ct*16 + ln15)*40 + q*8]);
        #pragma unroll
        for (int rt = 0; rt < 4; ++rt) {
            bf16x8 af = *(const bf16x8*)(&As[(wr + rt*16 + ln15)*40 + q*8]);
            #pragma unroll
            for (int ct = 0; ct < 4; ++ct)
                acc[rt][ct] = mfma_bf16(af, bfr[ct], acc[rt][ct]);
        }
    }
    float* po = part + (size_t)kz * (MROIS*HIDD);
    #pragma unroll
    for (int rt = 0; rt < 4; ++rt)
        #pragma unroll
        for (int ct = 0; ct < 4; ++ct)
            #pragma unroll
            for (int r = 0; r < 4; ++r) {
                int row = m0 + wr + rt*16 + q*4 + r;
                int col = n0 + wc + ct*16 + ln15;
                po[(size_t)row*HIDD + col] = acc[rt][ct][r];
            }
}

__global__ void k_fc1_red(const float* __restrict__ part, const float* __restrict__ bias,
                          float* __restrict__ h) {
    int idx = blockIdx.x*256 + threadIdx.x;   // < 524288
    float s = 0.f;
    #pragma unroll
    for (int k = 0; k < 16; ++k) s += part[(size_t)k*524288 + idx];
    h[idx] = fmaxf(s + bias[idx & 1023], 0.f);
}

// ---------------------------------------------------------------------------
// 3x3 conv as implicit GEMM (9 shifted taps), fused ReLU+bias+mean -> zmean
// Block = one box m, 4 waves x 64 oc = 256 oc. A staged in LDS [p][c_chunk32].
// ---------------------------------------------------------------------------
__launch_bounds__(256, 2)
__global__ void k_conv(const unsigned short* __restrict__ pooled, const unsigned short* __restrict__ wb,
                       const float* __restrict__ bconv, float* __restrict__ zmean) {
    __shared__ unsigned short As[196*40];
    int m = blockIdx.x;
    int t = threadIdx.x;
    int wave = t >> 6, ln = t & 63, ln15 = ln & 15, q = ln >> 4;
    int oc0 = wave * 64;
    float4v acc[4][13];
    #pragma unroll
    for (int i = 0; i < 4; ++i)
        #pragma unroll
        for (int j = 0; j < 13; ++j) acc[i][j] = (float4v){0.f,0.f,0.f,0.f};
    const unsigned short* pm = pooled + (size_t)m * NBINS * CCH;
    const short8 Z8 = {0,0,0,0,0,0,0,0};
    for (int ch = 0; ch < 16; ++ch) {
        int c0 = ch * 32;
        __syncthreads();
        #pragma unroll
        for (int i = 0; i < 4; ++i) {
            int g = t + i*256;
            if (g < 784) {
                int p = g >> 2, seg = g & 3;
                short8 v = *(const short8*)(pm + (size_t)p*CCH + c0 + seg*8);
                *(short8*)(&As[p*40 + seg*8]) = v;
            }
        }
        __syncthreads();
        #pragma unroll
        for (int pos = 0; pos < 9; ++pos) {
            int dy = pos/3 - 1, dx = pos%3 - 1;
            bf16x8 bfr[4];
            #pragma unroll
            for (int oct = 0; oct < 4; ++oct)
                bfr[oct] = *(const bf16x8*)(wb + (size_t)(pos*256 + oc0 + oct*16 + ln15)*CCH + c0 + q*8);
            #pragma unroll
            for (int rt = 0; rt < 13; ++rt) {
                int p = rt*16 + ln15;
                int y = p / 14, x = p % 14;
                int yy = y + dy, xx = x + dx;
                bool valid = (p < 196) && ((unsigned)yy < 14u) && ((unsigned)xx < 14u);
                bf16x8 af = __builtin_bit_cast(bf16x8, Z8);
                if (valid) af = *(const bf16x8*)(&As[(yy*14+xx)*40 + q*8]);
                #pragma unroll
                for (int oct = 0; oct < 4; ++oct)
                    acc[oct][rt] = mfma_bf16(af, bfr[oct], acc[oct][rt]);
            }
        }
    }
    #pragma unroll
    for (int oct = 0; oct < 4; ++oct) {
        float bias = bconv[oc0 + oct*16 + ln15];
        float s = 0.f;
        #pragma unroll
        for (int rt = 0; rt < 13; ++rt)
            #pragma unroll
            for (int r = 0; r < 4; ++r) {
                int p = rt*16 + q*4 + r;
                if (p < 196) s += fmaxf(acc[oct][rt][r] + bias, 0.f);
            }
        s += __shfl_xor(s, 16, 64);
        s += __shfl_xor(s, 32, 64);
        if (ln < 16) zmean[m*256 + oc0 + oct*16 + ln15] = s * (1.0f/196.0f);
    }
}

// ---------------------------------------------------------------------------
// cls/box heads: one block per box. softmax over 81.
// ---------------------------------------------------------------------------
__global__ void k_cls(const float* __restrict__ h, const float* __restrict__ wcls,
                      const float* __restrict__ bcls, const float* __restrict__ wbox,
                      const float* __restrict__ bbox, float* __restrict__ out) {
    __shared__ float hs[HIDD];
    __shared__ float sc[NCLS];
    __shared__ float red[2];
    int m = blockIdx.x, t = threadIdx.x;
    #pragma unroll
    for (int i = 0; i < 8; ++i) hs[t + i*128] = h[(size_t)m*HIDD + t + i*128];
    __syncthreads();
    if (t < NCLS) {
        float ac = bcls[t], ab = bbox[t];
        #pragma unroll 4
        for (int k = 0; k < HIDD; ++k) {
            float hv = hs[k];
            ac += hv * wcls[k*NCLS + t];
            ab += hv * wbox[k*NCLS + t];
        }
        sc[t] = ac;
        out[41472 + m*NCLS + t] = ab;
    }
    __syncthreads();
    if (t == 0) {
        float mx = -3.0e38f;
        for (int i = 0; i < NCLS; ++i) mx = fmaxf(mx, sc[i]);
        red[0] = mx;
    }
    __syncthreads();
    if (t < NCLS) sc[t] = expf(sc[t] - red[0]);
    __syncthreads();
    if (t == 0) {
        float sm = 0.f;
        for (int i = 0; i < NCLS; ++i) sm += sc[i];
        red[1] = sm;
    }
    __syncthreads();
    if (t < NCLS) out[m*NCLS + t] = sc[t] / red[1];
}

__global__ void k_mask(const float* __restrict__ zmean, const float* __restrict__ wm,
                       const float* __restrict__ bm, float* __restrict__ out) {
    __shared__ float zs[256];
    int m = blockIdx.x, t = threadIdx.x;
    #pragma unroll
    for (int i = 0; i < 2; ++i) zs[t + i*128] = zmean[m*256 + t + i*128];
    __syncthreads();
    if (t < NCLS) {
        float a = bm[t];
        #pragma unroll 4
        for (int k = 0; k < 256; ++k) a += zs[k] * wm[k*NCLS + t];
        out[82944 + m*NCLS + t] = 1.0f / (1.0f + expf(-a));
    }
}

// ---------------------------------------------------------------------------
extern "C" void kernel_launch(void* const* d_in, const int* in_sizes, int n_in,
                              void* d_out, int out_size, void* d_ws, size_t ws_size,
                              hipStream_t stream) {
    (void)in_sizes; (void)n_in; (void)out_size; (void)ws_size;
    const float* p2    = (const float*)d_in[0];
    const float* p3    = (const float*)d_in[1];
    const float* p4    = (const float*)d_in[2];
    const float* p5    = (const float*)d_in[3];
    const float* boxes = (const float*)d_in[4];
    const int*   bidx  = (const int*)d_in[5];
    const float* wfc1  = (const float*)d_in[6];
    const float* bfc1  = (const float*)d_in[7];
    const float* wcls  = (const float*)d_in[8];
    const float* bcls  = (const float*)d_in[9];
    const float* wbox  = (const float*)d_in[10];
    const float* bbox  = (const float*)d_in[11];
    const float* wconv = (const float*)d_in[12];
    const float* bconv = (const float*)d_in[13];
    const float* wmfc  = (const float*)d_in[14];
    const float* bmfc  = (const float*)d_in[15];
    const int*   imh   = (const int*)d_in[16];
    const int*   imw   = (const int*)d_in[17];

    char* ws = (char*)d_ws;
    unsigned short* pooled   = (unsigned short*)(ws);                    // 102,760,448 B
    unsigned short* packedB  = (unsigned short*)(ws + 102760448ull);     // 205,520,896 B
    unsigned short* wconvb   = (unsigned short*)(ws + 308281344ull);     //   2,359,296 B
    float*          partials = (float*)(ws + 310640640ull);              //  33,554,432 B
    float*          hbuf     = (float*)(ws + 344195072ull);              //   2,097,152 B
    float*          zmean    = (float*)(ws + 346292224ull);              //     524,288 B
    float*          out      = (float*)d_out;

    hipLaunchKernelGGL(k_pack_wconv, dim3(4608),  dim3(256), 0, stream, wconv, wconvb);
    hipLaunchKernelGGL(k_pack_wfc1,  dim3(50176), dim3(256), 0, stream, wfc1, packedB);
    hipLaunchKernelGGL(k_roi,  dim3(1024), dim3(256), 0, stream,
                       p2, p3, p4, p5, boxes, bidx, imh, imw, pooled);
    hipLaunchKernelGGL(k_conv, dim3(512),  dim3(256), 0, stream, pooled, wconvb, bconv, zmean);
    hipLaunchKernelGGL(k_fc1,  dim3(8,4,16), dim3(256), 0, stream, pooled, packedB, partials);
    hipLaunchKernelGGL(k_fc1_red, dim3(2048), dim3(256), 0, stream, partials, bfc1, hbuf);
    hipLaunchKernelGGL(k_cls,  dim3(512), dim3(128), 0, stream, hbuf, wcls, bcls, wbox, bbox, out);
    hipLaunchKernelGGL(k_mask, dim3(512), dim3(128), 0, stream, zmean, wmfc, bmfc, out);
}

// Round 2
// 1599.756 us; speedup vs baseline: 1.9425x; 1.9425x over previous
//
#include <hip/hip_runtime.h>
#include <hip/hip_bf16.h>

#define POOLN 14
#define NBINS 196
#define CCH 512
#define MROIS 512
#define HIDD 1024
#define NCLS 81
#define KTOT 100352  // 512*196

typedef short short8 __attribute__((ext_vector_type(8)));
typedef __bf16 bf16x8 __attribute__((ext_vector_type(8)));
typedef float float4v __attribute__((ext_vector_type(4)));

__device__ __forceinline__ float4v mfma_bf16(bf16x8 a, bf16x8 b, float4v c) {
    return __builtin_amdgcn_mfma_f32_16x16x32_bf16(a, b, c, 0, 0, 0);
}

__device__ __forceinline__ unsigned short f2bf(float v) {
    __hip_bfloat16 h = __float2bfloat16(v);
    return __builtin_bit_cast(unsigned short, h);
}
__device__ __forceinline__ float bflo(unsigned int u) {
    return __builtin_bit_cast(float, u << 16);
}
__device__ __forceinline__ float bfhi(unsigned int u) {
    return __builtin_bit_cast(float, u & 0xFFFF0000u);
}

// async global->LDS, 16B per lane; lds base must be wave-uniform (lane i lands at base + i*16)
__device__ __forceinline__ void gload16(const void* g, void* l) {
    __builtin_amdgcn_global_load_lds(
        (const __attribute__((address_space(1))) unsigned int*)g,
        (__attribute__((address_space(3))) unsigned int*)l, 16, 0, 0);
}

// ---------------------------------------------------------------------------
// Transpose features: [N,512,P] fp32 -> [N,P,512] bf16, LDS 64x64 tile.
// ---------------------------------------------------------------------------
__global__ void k_tr(const float* __restrict__ p2, const float* __restrict__ p3,
                     const float* __restrict__ p4, const float* __restrict__ p5,
                     unsigned short* __restrict__ f0, unsigned short* __restrict__ f1,
                     unsigned short* __restrict__ f2, unsigned short* __restrict__ f3) {
    __shared__ float tile[64 * 65];
    int pt = blockIdx.x;              // 0..831
    int n  = blockIdx.y >> 3;
    int c0 = (blockIdx.y & 7) * 64;
    const float* src; unsigned short* dst; int P;
    if (pt < 625)      { src = p2; dst = f0; P = 40000; }
    else if (pt < 782) { src = p3; dst = f1; P = 10000; pt -= 625; }
    else if (pt < 822) { src = p4; dst = f2; P = 2500;  pt -= 782; }
    else               { src = p5; dst = f3; P = 625;   pt -= 822; }
    int p0 = pt * 64;
    int t = threadIdx.x;
    #pragma unroll
    for (int i = 0; i < 16; ++i) {
        int idx = i * 256 + t;
        int pl = idx & 63, cl = idx >> 6;
        int p = p0 + pl;
        float v = 0.f;
        if (p < P) v = src[(size_t)(n * 512 + c0 + cl) * (size_t)P + p];
        tile[cl * 65 + pl] = v;
    }
    __syncthreads();
    #pragma unroll
    for (int i = 0; i < 8; ++i) {
        int idx = i * 256 + t;
        int cp = idx & 31, pl = idx >> 5;
        int p = p0 + pl;
        if (p < P) {
            unsigned int lo = (unsigned int)f2bf(tile[(cp * 2) * 65 + pl]);
            unsigned int hi = (unsigned int)f2bf(tile[(cp * 2 + 1) * 65 + pl]);
            *(unsigned int*)(dst + ((size_t)(n * (size_t)P + p) * 512 + c0 + cp * 2)) = lo | (hi << 16);
        }
    }
}

// ---------------------------------------------------------------------------
// RoIAlign from channel-last bf16 features. Block = box, thread = 2 channels.
// ---------------------------------------------------------------------------
__global__ void k_roi(const unsigned short* __restrict__ f0, const unsigned short* __restrict__ f1,
                      const unsigned short* __restrict__ f2, const unsigned short* __restrict__ f3,
                      const float* __restrict__ boxes, const int* __restrict__ bidx,
                      const int* __restrict__ imh, const int* __restrict__ imw,
                      unsigned short* __restrict__ pooled) {
    int m = blockIdx.x;
    int t = threadIdx.x;              // 256 threads, 2 ch each
    float b0 = boxes[m*4+0], b1 = boxes[m*4+1], b2 = boxes[m*4+2], b3 = boxes[m*4+3];
    int ih = imh[0], iw = imw[0];
    float alpha = (224.0f/800.0f) * (float)(ih < iw ? ih : iw);
    float bw = fabsf(b2-b0), bh = fabsf(b3-b1);
    float s = sqrtf(fmaxf(bw*bh, 1e-6f));
    float kf = floorf(4.0f + log2f(s/alpha)) - 2.0f;
    int lvl = (int)fminf(fmaxf(kf, 0.0f), 3.0f);
    const unsigned short* f = lvl==0 ? f0 : (lvl==1 ? f1 : (lvl==2 ? f2 : f3));
    int W = 200 >> lvl;
    int P = W * W;
    float scale = 1.0f / (float)(4 << lvl);
    float x1s=b0*scale, y1s=b1*scale, x2s=b2*scale, y2s=b3*scale;
    const unsigned short* fb = f + (size_t)bidx[m] * (size_t)P * 512 + 2*t;
    unsigned short* outp = pooled + (size_t)m * NBINS * CCH + 2*t;
    float Wm1 = (float)(W-1);
    for (int py = 0; py < POOLN; ++py) {
        float gy = ((float)py + 0.5f) / 14.0f;
        float ys = y1s + gy * (y2s - y1s);
        float y0f = floorf(ys);
        float ly = ys - y0f;
        int y0 = (int)fminf(fmaxf(y0f, 0.0f), Wm1);
        int y1 = (int)fminf(fmaxf(y0f+1.0f, 0.0f), Wm1);
        #pragma unroll
        for (int px = 0; px < POOLN; ++px) {
            float gx = ((float)px + 0.5f) / 14.0f;
            float xs = x1s + gx * (x2s - x1s);
            float x0f = floorf(xs);
            float lx = xs - x0f;
            int x0 = (int)fminf(fmaxf(x0f, 0.0f), Wm1);
            int x1 = (int)fminf(fmaxf(x0f+1.0f, 0.0f), Wm1);
            unsigned int u00 = *(const unsigned int*)(fb + (size_t)(y0*W + x0) * 512);
            unsigned int u01 = *(const unsigned int*)(fb + (size_t)(y0*W + x1) * 512);
            unsigned int u10 = *(const unsigned int*)(fb + (size_t)(y1*W + x0) * 512);
            unsigned int u11 = *(const unsigned int*)(fb + (size_t)(y1*W + x1) * 512);
            float w00 = (1.0f-ly)*(1.0f-lx), w01 = (1.0f-ly)*lx;
            float w10 = ly*(1.0f-lx),        w11 = ly*lx;
            float vlo = bflo(u00)*w00 + bflo(u01)*w01 + bflo(u10)*w10 + bflo(u11)*w11;
            float vhi = bfhi(u00)*w00 + bfhi(u01)*w01 + bfhi(u10)*w10 + bfhi(u11)*w11;
            unsigned int r = (unsigned int)f2bf(vlo) | ((unsigned int)f2bf(vhi) << 16);
            *(unsigned int*)(outp + (size_t)(py*POOLN + px) * CCH) = r;
        }
    }
}

// ---------------------------------------------------------------------------
// Pre-pack w_fc1 fp32 [k=c*196+p][n] -> bf16 packed [k'/8][n][8], k' = p*512+c
// ---------------------------------------------------------------------------
__global__ void k_pack_wfc1(const float* __restrict__ w, unsigned short* __restrict__ pk) {
    int g = blockIdx.x * 256 + threadIdx.x;   // < 12544*1024
    int n = g & 1023;
    int k8 = g >> 10;
    int kp = k8 << 3;
    int p  = kp >> 9;
    int cc = kp & 511;
    short8 hv;
    #pragma unroll
    for (int j = 0; j < 8; ++j) {
        float v = w[(size_t)((cc+j)*NBINS + p) * HIDD + n];
        hv[j] = (short)f2bf(v);
    }
    *(short8*)(pk + (size_t)g * 8) = hv;
}

// w_conv fp32 [oc][c][3][3] -> bf16 [tap][oc][c]
__global__ void k_pack_wconv(const float* __restrict__ w, unsigned short* __restrict__ wb) {
    int g = blockIdx.x * 256 + threadIdx.x;   // < 9*256*512
    int c  = g & 511;
    int oc = (g >> 9) & 255;
    int kk = g >> 17;
    wb[g] = f2bf(w[(size_t)(oc*512 + c)*9 + kk]);
}

// ---------------------------------------------------------------------------
// fc1 GEMM: [512,100352]x[100352,1024], BM=256, BN=128, split-K=16
// global_load_lds staging, unpadded LDS rows of 32 ushort.
// ---------------------------------------------------------------------------
__launch_bounds__(256, 1)
__global__ void k_fc1(const unsigned short* __restrict__ A, const unsigned short* __restrict__ B,
                      float* __restrict__ part) {
    __shared__ unsigned short As[256*32];   // 16 KB
    __shared__ unsigned short Bs[128*32];   // 8 KB
    int t = threadIdx.x;
    int n0 = blockIdx.x * 128;
    int m0 = blockIdx.y * 256;
    int kz = blockIdx.z;
    int wave = t >> 6, ln = t & 63, ln15 = ln & 15, q = ln >> 4;
    int wr = (wave >> 1) * 128, wc = (wave & 1) * 64;
    int seg = ln & 3, rsub = ln >> 2;
    float4v acc[8][4];
    #pragma unroll
    for (int i = 0; i < 8; ++i)
        #pragma unroll
        for (int j = 0; j < 4; ++j) acc[i][j] = (float4v){0.f,0.f,0.f,0.f};
    int kbase = kz * 6272;
    for (int it = 0; it < 196; ++it) {
        int k0 = kbase + it*32;
        __syncthreads();
        #pragma unroll
        for (int i = 0; i < 4; ++i) {
            int row = i*64 + wave*16 + rsub;
            gload16(A + (size_t)(m0+row)*KTOT + k0 + seg*8, &As[(i*64 + wave*16)*32]);
        }
        #pragma unroll
        for (int i = 0; i < 2; ++i) {
            int nl = i*64 + wave*16 + rsub;
            gload16(B + ((size_t)((k0 >> 3) + seg)*1024 + n0 + nl)*8, &Bs[(i*64 + wave*16)*32]);
        }
        __syncthreads();
        bf16x8 bfr[4];
        #pragma unroll
        for (int ct = 0; ct < 4; ++ct)
            bfr[ct] = *(const bf16x8*)(&Bs[(wc + ct*16 + ln15)*32 + q*8]);
        #pragma unroll
        for (int rt = 0; rt < 8; ++rt) {
            bf16x8 af = *(const bf16x8*)(&As[(wr + rt*16 + ln15)*32 + q*8]);
            #pragma unroll
            for (int ct = 0; ct < 4; ++ct)
                acc[rt][ct] = mfma_bf16(af, bfr[ct], acc[rt][ct]);
        }
    }
    float* po = part + (size_t)kz * (MROIS*HIDD);
    #pragma unroll
    for (int rt = 0; rt < 8; ++rt)
        #pragma unroll
        for (int ct = 0; ct < 4; ++ct)
            #pragma unroll
            for (int r = 0; r < 4; ++r) {
                int row = m0 + wr + rt*16 + q*4 + r;
                int col = n0 + wc + ct*16 + ln15;
                po[(size_t)row*HIDD + col] = acc[rt][ct][r];
            }
}

__global__ void k_fc1_red(const float* __restrict__ part, const float* __restrict__ bias,
                          float* __restrict__ h) {
    int idx = blockIdx.x*256 + threadIdx.x;   // < 524288
    float s = 0.f;
    #pragma unroll
    for (int k = 0; k < 16; ++k) s += part[(size_t)k*524288 + idx];
    h[idx] = fmaxf(s + bias[idx & 1023], 0.f);
}

// ---------------------------------------------------------------------------
// 3x3 conv as implicit GEMM, fused ReLU+bias+mean -> zmean.
// Block = box, 512 thr / 8 waves: wave = (mh, og); og -> 64 oc, mh -> 7 rt tiles.
// ---------------------------------------------------------------------------
__launch_bounds__(512, 1)
__global__ void k_conv(const unsigned short* __restrict__ pooled, const unsigned short* __restrict__ wb,
                       const float* __restrict__ bconv, float* __restrict__ zmean) {
    __shared__ unsigned short As[208*32];   // 13.3 KB, rows = bins (halo-masked), unpadded
    __shared__ float sred[2][256];
    int m = blockIdx.x;
    int t = threadIdx.x;
    int wave = t >> 6, ln = t & 63, ln15 = ln & 15, q = ln >> 4;
    int og = wave & 3, mh = wave >> 2;
    int oc0 = og * 64;
    int rt0 = mh * 7;
    float4v acc[4][7];
    #pragma unroll
    for (int i = 0; i < 4; ++i)
        #pragma unroll
        for (int j = 0; j < 7; ++j) acc[i][j] = (float4v){0.f,0.f,0.f,0.f};
    const unsigned short* pm = pooled + (size_t)m * NBINS * CCH;
    const short8 Z8 = {0,0,0,0,0,0,0,0};
    int seg = ln & 3, rsub = ln >> 2;
    for (int ch = 0; ch < 16; ++ch) {
        int c0 = ch * 32;
        __syncthreads();
        #pragma unroll
        for (int i = 0; i < 2; ++i) {
            int wg = i*8 + wave;           // 13 wave-groups of 16 rows
            if (wg < 13) {
                int row = wg*16 + rsub;
                int rrow = row < 196 ? row : 195;   // clamp: avoid OOB read past pooled
                gload16(pm + (size_t)rrow*CCH + c0 + seg*8, &As[(wg*16)*32]);
            }
        }
        __syncthreads();
        #pragma unroll
        for (int pos = 0; pos < 9; ++pos) {
            int dy = pos/3 - 1, dx = pos%3 - 1;
            bf16x8 bfr[4];
            #pragma unroll
            for (int oct = 0; oct < 4; ++oct)
                bfr[oct] = *(const bf16x8*)(wb + (size_t)(pos*256 + oc0 + oct*16 + ln15)*CCH + c0 + q*8);
            #pragma unroll
            for (int rr = 0; rr < 7; ++rr) {
                int rt = rt0 + rr;
                int p = rt*16 + ln15;
                int y = p / 14, x = p % 14;
                int yy = y + dy, xx = x + dx;
                bool valid = (p < 196) && ((unsigned)yy < 14u) && ((unsigned)xx < 14u);
                bf16x8 af = __builtin_bit_cast(bf16x8, Z8);
                if (valid) af = *(const bf16x8*)(&As[(yy*14+xx)*32 + q*8]);
                #pragma unroll
                for (int oct = 0; oct < 4; ++oct)
                    acc[oct][rr] = mfma_bf16(af, bfr[oct], acc[oct][rr]);
            }
        }
    }
    #pragma unroll
    for (int oct = 0; oct < 4; ++oct) {
        float b = bconv[oc0 + oct*16 + ln15];
        float s = 0.f;
        #pragma unroll
        for (int rr = 0; rr < 7; ++rr) {
            int rt = rt0 + rr;
            #pragma unroll
            for (int r = 0; r < 4; ++r) {
                int p = rt*16 + q*4 + r;
                if (p < 196) s += fmaxf(acc[oct][rr][r] + b, 0.f);
            }
        }
        s += __shfl_xor(s, 16, 64);
        s += __shfl_xor(s, 32, 64);
        if (ln < 16) sred[mh][oc0 + oct*16 + ln15] = s;
    }
    __syncthreads();
    if (t < 256) zmean[m*256 + t] = (sred[0][t] + sred[1][t]) * (1.0f/196.0f);
}

// ---------------------------------------------------------------------------
// cls/box heads: one block per box. softmax over 81.
// ---------------------------------------------------------------------------
__global__ void k_cls(const float* __restrict__ h, const float* __restrict__ wcls,
                      const float* __restrict__ bcls, const float* __restrict__ wbox,
                      const float* __restrict__ bbox, float* __restrict__ out) {
    __shared__ float hs[HIDD];
    __shared__ float sc[NCLS];
    __shared__ float red[2];
    int m = blockIdx.x, t = threadIdx.x;
    #pragma unroll
    for (int i = 0; i < 8; ++i) hs[t + i*128] = h[(size_t)m*HIDD + t + i*128];
    __syncthreads();
    if (t < NCLS) {
        float ac = bcls[t], ab = bbox[t];
        #pragma unroll 4
        for (int k = 0; k < HIDD; ++k) {
            float hv = hs[k];
            ac += hv * wcls[k*NCLS + t];
            ab += hv * wbox[k*NCLS + t];
        }
        sc[t] = ac;
        out[41472 + m*NCLS + t] = ab;
    }
    __syncthreads();
    if (t == 0) {
        float mx = -3.0e38f;
        for (int i = 0; i < NCLS; ++i) mx = fmaxf(mx, sc[i]);
        red[0] = mx;
    }
    __syncthreads();
    if (t < NCLS) sc[t] = expf(sc[t] - red[0]);
    __syncthreads();
    if (t == 0) {
        float sm = 0.f;
        for (int i = 0; i < NCLS; ++i) sm += sc[i];
        red[1] = sm;
    }
    __syncthreads();
    if (t < NCLS) out[m*NCLS + t] = sc[t] / red[1];
}

__global__ void k_mask(const float* __restrict__ zmean, const float* __restrict__ wm,
                       const float* __restrict__ bm, float* __restrict__ out) {
    __shared__ float zs[256];
    int m = blockIdx.x, t = threadIdx.x;
    #pragma unroll
    for (int i = 0; i < 2; ++i) zs[t + i*128] = zmean[m*256 + t + i*128];
    __syncthreads();
    if (t < NCLS) {
        float a = bm[t];
        #pragma unroll 4
        for (int k = 0; k < 256; ++k) a += zs[k] * wm[k*NCLS + t];
        out[82944 + m*NCLS + t] = 1.0f / (1.0f + expf(-a));
    }
}

// ---------------------------------------------------------------------------
extern "C" void kernel_launch(void* const* d_in, const int* in_sizes, int n_in,
                              void* d_out, int out_size, void* d_ws, size_t ws_size,
                              hipStream_t stream) {
    (void)in_sizes; (void)n_in; (void)out_size; (void)ws_size;
    const float* p2    = (const float*)d_in[0];
    const float* p3    = (const float*)d_in[1];
    const float* p4    = (const float*)d_in[2];
    const float* p5    = (const float*)d_in[3];
    const float* boxes = (const float*)d_in[4];
    const int*   bidx  = (const int*)d_in[5];
    const float* wfc1  = (const float*)d_in[6];
    const float* bfc1  = (const float*)d_in[7];
    const float* wcls  = (const float*)d_in[8];
    const float* bcls  = (const float*)d_in[9];
    const float* wbox  = (const float*)d_in[10];
    const float* bbox  = (const float*)d_in[11];
    const float* wconv = (const float*)d_in[12];
    const float* bconv = (const float*)d_in[13];
    const float* wmfc  = (const float*)d_in[14];
    const float* bmfc  = (const float*)d_in[15];
    const int*   imh   = (const int*)d_in[16];
    const int*   imw   = (const int*)d_in[17];

    // Workspace layout (total 346,816,512 B, same as round-1 known-good):
    //   [0, 205520896)        packedB  -- ALSO aliases transposed features fpt
    //                         (fpt dies after k_roi; k_pack_wfc1 runs after k_roi)
    //   [205520896,239075328) partials (33.5 MB)
    //   [239075328,241172480) hbuf
    //   [241172480,241696768) zmean
    //   [241696768,244056064) wconvb
    //   [244056064,346816512) pooled (102.76 MB)
    char* ws = (char*)d_ws;
    unsigned short* fpt0     = (unsigned short*)(ws);                    // 81,920,000 B
    unsigned short* fpt1     = (unsigned short*)(ws + 81920000ull);      // 20,480,000 B
    unsigned short* fpt2     = (unsigned short*)(ws + 102400000ull);     //  5,120,000 B
    unsigned short* fpt3     = (unsigned short*)(ws + 107520000ull);     //  1,280,000 B
    unsigned short* packedB  = (unsigned short*)(ws);                    // 205,520,896 B (after roi)
    float*          partials = (float*)(ws + 205520896ull);
    float*          hbuf     = (float*)(ws + 239075328ull);
    float*          zmean    = (float*)(ws + 241172480ull);
    unsigned short* wconvb   = (unsigned short*)(ws + 241696768ull);
    unsigned short* pooled   = (unsigned short*)(ws + 244056064ull);
    float*          out      = (float*)d_out;

    hipLaunchKernelGGL(k_tr, dim3(832, 16), dim3(256), 0, stream,
                       p2, p3, p4, p5, fpt0, fpt1, fpt2, fpt3);
    hipLaunchKernelGGL(k_roi, dim3(512), dim3(256), 0, stream,
                       fpt0, fpt1, fpt2, fpt3, boxes, bidx, imh, imw, pooled);
    hipLaunchKernelGGL(k_pack_wfc1,  dim3(50176), dim3(256), 0, stream, wfc1, packedB);
    hipLaunchKernelGGL(k_pack_wconv, dim3(4608),  dim3(256), 0, stream, wconv, wconvb);
    hipLaunchKernelGGL(k_conv, dim3(512),  dim3(512), 0, stream, pooled, wconvb, bconv, zmean);
    hipLaunchKernelGGL(k_fc1,  dim3(8, 2, 16), dim3(256), 0, stream, pooled, packedB, partials);
    hipLaunchKernelGGL(k_fc1_red, dim3(2048), dim3(256), 0, stream, partials, bfc1, hbuf);
    hipLaunchKernelGGL(k_cls,  dim3(512), dim3(128), 0, stream, hbuf, wcls, bcls, wbox, bbox, out);
    hipLaunchKernelGGL(k_mask, dim3(512), dim3(128), 0, stream, zmean, wmfc, bmfc, out);
}

// Round 3
// 1547.119 us; speedup vs baseline: 2.0086x; 1.0340x over previous
//
#include <hip/hip_runtime.h>
#include <hip/hip_bf16.h>

#define POOLN 14
#define NBINS 196
#define CCH 512
#define MROIS 512
#define HIDD 1024
#define NCLS 81
#define KTOT 100352  // 512*196

typedef short short8 __attribute__((ext_vector_type(8)));
typedef __bf16 bf16x8 __attribute__((ext_vector_type(8)));
typedef float float4v __attribute__((ext_vector_type(4)));

__device__ __forceinline__ float4v mfma_bf16(bf16x8 a, bf16x8 b, float4v c) {
    return __builtin_amdgcn_mfma_f32_16x16x32_bf16(a, b, c, 0, 0, 0);
}

__device__ __forceinline__ unsigned short f2bf(float v) {
    __hip_bfloat16 h = __float2bfloat16(v);
    return __builtin_bit_cast(unsigned short, h);
}
__device__ __forceinline__ float bflo(unsigned int u) {
    return __builtin_bit_cast(float, u << 16);
}
__device__ __forceinline__ float bfhi(unsigned int u) {
    return __builtin_bit_cast(float, u & 0xFFFF0000u);
}

// async global->LDS, 16B per lane; lds base must be wave-uniform (lane i lands at base + i*16)
__device__ __forceinline__ void gload16(const void* g, void* l) {
    __builtin_amdgcn_global_load_lds(
        (const __attribute__((address_space(1))) unsigned int*)g,
        (__attribute__((address_space(3))) unsigned int*)l, 16, 0, 0);
}

// ---------------------------------------------------------------------------
// Transpose features: [N,512,P] fp32 -> [N,P,512] bf16, LDS 64x64 tile.
// ---------------------------------------------------------------------------
__global__ void k_tr(const float* __restrict__ p2, const float* __restrict__ p3,
                     const float* __restrict__ p4, const float* __restrict__ p5,
                     unsigned short* __restrict__ f0, unsigned short* __restrict__ f1,
                     unsigned short* __restrict__ f2, unsigned short* __restrict__ f3) {
    __shared__ float tile[64 * 65];
    int pt = blockIdx.x;              // 0..831
    int n  = blockIdx.y >> 3;
    int c0 = (blockIdx.y & 7) * 64;
    const float* src; unsigned short* dst; int P;
    if (pt < 625)      { src = p2; dst = f0; P = 40000; }
    else if (pt < 782) { src = p3; dst = f1; P = 10000; pt -= 625; }
    else if (pt < 822) { src = p4; dst = f2; P = 2500;  pt -= 782; }
    else               { src = p5; dst = f3; P = 625;   pt -= 822; }
    int p0 = pt * 64;
    int t = threadIdx.x;
    #pragma unroll
    for (int i = 0; i < 16; ++i) {
        int idx = i * 256 + t;
        int pl = idx & 63, cl = idx >> 6;
        int p = p0 + pl;
        float v = 0.f;
        if (p < P) v = src[(size_t)(n * 512 + c0 + cl) * (size_t)P + p];
        tile[cl * 65 + pl] = v;
    }
    __syncthreads();
    #pragma unroll
    for (int i = 0; i < 8; ++i) {
        int idx = i * 256 + t;
        int cp = idx & 31, pl = idx >> 5;
        int p = p0 + pl;
        if (p < P) {
            unsigned int lo = (unsigned int)f2bf(tile[(cp * 2) * 65 + pl]);
            unsigned int hi = (unsigned int)f2bf(tile[(cp * 2 + 1) * 65 + pl]);
            *(unsigned int*)(dst + ((size_t)(n * (size_t)P + p) * 512 + c0 + cp * 2)) = lo | (hi << 16);
        }
    }
}

// ---------------------------------------------------------------------------
// RoIAlign from channel-last bf16 features. Block = box, thread = 2 channels.
// ---------------------------------------------------------------------------
__global__ void k_roi(const unsigned short* __restrict__ f0, const unsigned short* __restrict__ f1,
                      const unsigned short* __restrict__ f2, const unsigned short* __restrict__ f3,
                      const float* __restrict__ boxes, const int* __restrict__ bidx,
                      const int* __restrict__ imh, const int* __restrict__ imw,
                      unsigned short* __restrict__ pooled) {
    int m = blockIdx.x;
    int t = threadIdx.x;              // 256 threads, 2 ch each
    float b0 = boxes[m*4+0], b1 = boxes[m*4+1], b2 = boxes[m*4+2], b3 = boxes[m*4+3];
    int ih = imh[0], iw = imw[0];
    float alpha = (224.0f/800.0f) * (float)(ih < iw ? ih : iw);
    float bw = fabsf(b2-b0), bh = fabsf(b3-b1);
    float s = sqrtf(fmaxf(bw*bh, 1e-6f));
    float kf = floorf(4.0f + log2f(s/alpha)) - 2.0f;
    int lvl = (int)fminf(fmaxf(kf, 0.0f), 3.0f);
    const unsigned short* f = lvl==0 ? f0 : (lvl==1 ? f1 : (lvl==2 ? f2 : f3));
    int W = 200 >> lvl;
    int P = W * W;
    float scale = 1.0f / (float)(4 << lvl);
    float x1s=b0*scale, y1s=b1*scale, x2s=b2*scale, y2s=b3*scale;
    const unsigned short* fb = f + (size_t)bidx[m] * (size_t)P * 512 + 2*t;
    unsigned short* outp = pooled + (size_t)m * NBINS * CCH + 2*t;
    float Wm1 = (float)(W-1);
    for (int py = 0; py < POOLN; ++py) {
        float gy = ((float)py + 0.5f) / 14.0f;
        float ys = y1s + gy * (y2s - y1s);
        float y0f = floorf(ys);
        float ly = ys - y0f;
        int y0 = (int)fminf(fmaxf(y0f, 0.0f), Wm1);
        int y1 = (int)fminf(fmaxf(y0f+1.0f, 0.0f), Wm1);
        #pragma unroll
        for (int px = 0; px < POOLN; ++px) {
            float gx = ((float)px + 0.5f) / 14.0f;
            float xs = x1s + gx * (x2s - x1s);
            float x0f = floorf(xs);
            float lx = xs - x0f;
            int x0 = (int)fminf(fmaxf(x0f, 0.0f), Wm1);
            int x1 = (int)fminf(fmaxf(x0f+1.0f, 0.0f), Wm1);
            unsigned int u00 = *(const unsigned int*)(fb + (size_t)(y0*W + x0) * 512);
            unsigned int u01 = *(const unsigned int*)(fb + (size_t)(y0*W + x1) * 512);
            unsigned int u10 = *(const unsigned int*)(fb + (size_t)(y1*W + x0) * 512);
            unsigned int u11 = *(const unsigned int*)(fb + (size_t)(y1*W + x1) * 512);
            float w00 = (1.0f-ly)*(1.0f-lx), w01 = (1.0f-ly)*lx;
            float w10 = ly*(1.0f-lx),        w11 = ly*lx;
            float vlo = bflo(u00)*w00 + bflo(u01)*w01 + bflo(u10)*w10 + bflo(u11)*w11;
            float vhi = bfhi(u00)*w00 + bfhi(u01)*w01 + bfhi(u10)*w10 + bfhi(u11)*w11;
            unsigned int r = (unsigned int)f2bf(vlo) | ((unsigned int)f2bf(vhi) << 16);
            *(unsigned int*)(outp + (size_t)(py*POOLN + px) * CCH) = r;
        }
    }
}

// ---------------------------------------------------------------------------
// Pre-pack w_fc1 fp32 [k=c*196+p][n] -> bf16 packed [k'/8][n][8], k' = p*512+c
// ---------------------------------------------------------------------------
__global__ void k_pack_wfc1(const float* __restrict__ w, unsigned short* __restrict__ pk) {
    int g = blockIdx.x * 256 + threadIdx.x;   // < 12544*1024
    int n = g & 1023;
    int k8 = g >> 10;
    int kp = k8 << 3;
    int p  = kp >> 9;
    int cc = kp & 511;
    short8 hv;
    #pragma unroll
    for (int j = 0; j < 8; ++j) {
        float v = w[(size_t)((cc+j)*NBINS + p) * HIDD + n];
        hv[j] = (short)f2bf(v);
    }
    *(short8*)(pk + (size_t)g * 8) = hv;
}

// w_conv fp32 [oc][c][3][3] -> bf16 [tap][oc][c]; tail blocks zero zmean
__global__ void k_pack_wconv(const float* __restrict__ w, unsigned short* __restrict__ wb,
                             float* __restrict__ zmean) {
    if (blockIdx.x >= 4608) {
        int z = (blockIdx.x - 4608) * 256 + threadIdx.x;   // < 131072
        zmean[z] = 0.f;
        return;
    }
    int g = blockIdx.x * 256 + threadIdx.x;   // < 9*256*512
    int c  = g & 511;
    int oc = (g >> 9) & 255;
    int kk = g >> 17;
    wb[g] = f2bf(w[(size_t)(oc*512 + c)*9 + kk]);
}

// wcls|wbox fp32 [k][81] -> whb bf16 [n=176][k=1024] (rows >=162 zero)
__global__ void k_pack_whead(const float* __restrict__ wcls, const float* __restrict__ wbox,
                             unsigned short* __restrict__ whb) {
    int g = blockIdx.x * 256 + threadIdx.x;   // < 176*1024
    int n = g >> 10, k = g & 1023;
    float v = 0.f;
    if (n < 81)       v = wcls[k*NCLS + n];
    else if (n < 162) v = wbox[k*NCLS + (n-81)];
    whb[g] = f2bf(v);
}

// ---------------------------------------------------------------------------
// fc1 GEMM: [512,100352]x[100352,1024], BM=256, BN=128, split-K=16
// ---------------------------------------------------------------------------
__launch_bounds__(256, 1)
__global__ void k_fc1(const unsigned short* __restrict__ A, const unsigned short* __restrict__ B,
                      float* __restrict__ part) {
    __shared__ unsigned short As[256*32];   // 16 KB
    __shared__ unsigned short Bs[128*32];   // 8 KB
    int t = threadIdx.x;
    int n0 = blockIdx.x * 128;
    int m0 = blockIdx.y * 256;
    int kz = blockIdx.z;
    int wave = t >> 6, ln = t & 63, ln15 = ln & 15, q = ln >> 4;
    int wr = (wave >> 1) * 128, wc = (wave & 1) * 64;
    int seg = ln & 3, rsub = ln >> 2;
    float4v acc[8][4];
    #pragma unroll
    for (int i = 0; i < 8; ++i)
        #pragma unroll
        for (int j = 0; j < 4; ++j) acc[i][j] = (float4v){0.f,0.f,0.f,0.f};
    int kbase = kz * 6272;
    for (int it = 0; it < 196; ++it) {
        int k0 = kbase + it*32;
        __syncthreads();
        #pragma unroll
        for (int i = 0; i < 4; ++i) {
            int row = i*64 + wave*16 + rsub;
            gload16(A + (size_t)(m0+row)*KTOT + k0 + seg*8, &As[(i*64 + wave*16)*32]);
        }
        #pragma unroll
        for (int i = 0; i < 2; ++i) {
            int nl = i*64 + wave*16 + rsub;
            gload16(B + ((size_t)((k0 >> 3) + seg)*1024 + n0 + nl)*8, &Bs[(i*64 + wave*16)*32]);
        }
        __syncthreads();
        bf16x8 bfr[4];
        #pragma unroll
        for (int ct = 0; ct < 4; ++ct)
            bfr[ct] = *(const bf16x8*)(&Bs[(wc + ct*16 + ln15)*32 + q*8]);
        #pragma unroll
        for (int rt = 0; rt < 8; ++rt) {
            bf16x8 af = *(const bf16x8*)(&As[(wr + rt*16 + ln15)*32 + q*8]);
            #pragma unroll
            for (int ct = 0; ct < 4; ++ct)
                acc[rt][ct] = mfma_bf16(af, bfr[ct], acc[rt][ct]);
        }
    }
    float* po = part + (size_t)kz * (MROIS*HIDD);
    #pragma unroll
    for (int rt = 0; rt < 8; ++rt)
        #pragma unroll
        for (int ct = 0; ct < 4; ++ct)
            #pragma unroll
            for (int r = 0; r < 4; ++r) {
                int row = m0 + wr + rt*16 + q*4 + r;
                int col = n0 + wc + ct*16 + ln15;
                po[(size_t)row*HIDD + col] = acc[rt][ct][r];
            }
}

// reduce partials + bias + relu -> h bf16
__global__ void k_fc1_red(const float* __restrict__ part, const float* __restrict__ bias,
                          unsigned short* __restrict__ hb) {
    int idx = blockIdx.x*256 + threadIdx.x;   // < 524288
    float s = 0.f;
    #pragma unroll
    for (int k = 0; k < 16; ++k) s += part[(size_t)k*524288 + idx];
    hb[idx] = f2bf(fmaxf(s + bias[idx & 1023], 0.f));
}

// ---------------------------------------------------------------------------
// 3x3 conv implicit GEMM, halo-padded LDS, fused ReLU+bias+mean (atomic).
// Grid (2, 512): blockIdx.x = bin-half mh, blockIdx.y = box. 256 thr / 4 waves.
// Wave w handles oc 64*w..64*w+63 over 98 bins (7 rt tiles of 16 slots).
// LDS tile: 10 y-rows x 16 x-slots x (32ch + 8 pad) ushort, borders stay zero.
// ---------------------------------------------------------------------------
__launch_bounds__(256, 2)
__global__ void k_conv(const unsigned short* __restrict__ pooled, const unsigned short* __restrict__ wb,
                       const float* __restrict__ bconv, float* __restrict__ zmean) {
    __shared__ unsigned short As[161*40 + 8];   // 12896 B, slot (r*16+xs)*40
    int mh = blockIdx.x;
    int m  = blockIdx.y;
    int t = threadIdx.x;
    int wave = t >> 6, ln = t & 63, ln15 = ln & 15, q = ln >> 4;
    int oc0 = wave * 64;
    // zero whole LDS once; data slots are overwritten each iter, borders stay 0
    {
        unsigned int* a32 = (unsigned int*)As;
        #pragma unroll
        for (int i = 0; i < 13; ++i) {
            int idx = i*256 + t;
            if (idx < 3224) a32[idx] = 0u;
        }
    }
    // per-rr LDS fragment offsets (ushort units): lp = rr*16+ln15
    int soff[7];
    #pragma unroll
    for (int rr = 0; rr < 7; ++rr) {
        int lp = rr*16 + ln15;
        int yl = lp / 14, xl = lp - yl*14;
        soff[rr] = ((yl + 1)*16 + xl + 1)*40 + q*8;
    }
    float4v acc[4][7];
    #pragma unroll
    for (int i = 0; i < 4; ++i)
        #pragma unroll
        for (int j = 0; j < 7; ++j) acc[i][j] = (float4v){0.f,0.f,0.f,0.f};
    const unsigned short* pm = pooled + (size_t)m * NBINS * CCH + (size_t)mh * 84 * CCH;
    // staged bin b (0..111): global p = mh*98? no: rows y: mh=0 -> y 0..7 (p=b),
    // mh=1 -> y 6..13 (p=84+b). pm already offset by mh*84 rows.
    int sb0 = t >> 2, sseg0 = t & 3;             // staging task split
    for (int ch = 0; ch < 16; ++ch) {
        int c0 = ch * 32;
        __syncthreads();
        #pragma unroll
        for (int i = 0; i < 2; ++i) {
            int g = i*256 + t;
            if (g < 448) {
                int b = g >> 2, seg = g & 3;
                int yl = b / 14, xl = b - yl*14;
                int r = yl + 1 - mh;             // mh=0: r=yl+1 (y=r-1); mh=1: r=yl (y=6+yl)
                short8 v = *(const short8*)(pm + (size_t)b*CCH + c0 + seg*8);
                *(short8*)(&As[(r*16 + xl + 1)*40 + seg*8]) = v;
            }
        }
        __syncthreads();
        #pragma unroll
        for (int pos = 0; pos < 9; ++pos) {
            const int dy = pos/3 - 1, dx = pos%3 - 1;
            bf16x8 bfr[4];
            #pragma unroll
            for (int oct = 0; oct < 4; ++oct)
                bfr[oct] = *(const bf16x8*)(wb + (size_t)(pos*256 + oc0 + oct*16 + ln15)*CCH + c0 + q*8);
            #pragma unroll
            for (int rr = 0; rr < 7; ++rr) {
                bf16x8 af = *(const bf16x8*)(&As[soff[rr] + (dy*16 + dx)*40]);
                #pragma unroll
                for (int oct = 0; oct < 4; ++oct)
                    acc[oct][rr] = mfma_bf16(af, bfr[oct], acc[oct][rr]);
            }
        }
    }
    // epilogue: per-bin bias+relu, partial mean over this block's 98 bins, atomic add
    #pragma unroll
    for (int oct = 0; oct < 4; ++oct) {
        float b = bconv[oc0 + oct*16 + ln15];
        float s = 0.f;
        #pragma unroll
        for (int rr = 0; rr < 7; ++rr)
            #pragma unroll
            for (int r = 0; r < 4; ++r) {
                int lp = rr*16 + q*4 + r;
                if (lp < 98) s += fmaxf(acc[oct][rr][r] + b, 0.f);
            }
        s += __shfl_xor(s, 16, 64);
        s += __shfl_xor(s, 32, 64);
        if (ln < 16) atomicAdd(&zmean[m*256 + oc0 + oct*16 + ln15], s * (1.0f/196.0f));
    }
}

// ---------------------------------------------------------------------------
// cls+box head GEMM: h[512,1024] bf16 x whb^T[176,1024] -> sc / box out.
// Grid 4 (m-tiles of 128), 256 thr / 4 waves; wave = 32 rows x 176 cols.
// ---------------------------------------------------------------------------
__launch_bounds__(256, 1)
__global__ void k_head(const unsigned short* __restrict__ hb, const unsigned short* __restrict__ whb,
                       const float* __restrict__ bcls, const float* __restrict__ bbox,
                       float* __restrict__ sc, float* __restrict__ out) {
    __shared__ unsigned short Ahs[128*40];
    int t = threadIdx.x;
    int m0 = blockIdx.x * 128;
    int wave = t >> 6, ln = t & 63, ln15 = ln & 15, q = ln >> 4;
    int wr = wave * 32;
    float4v acc[2][11];
    #pragma unroll
    for (int i = 0; i < 2; ++i)
        #pragma unroll
        for (int j = 0; j < 11; ++j) acc[i][j] = (float4v){0.f,0.f,0.f,0.f};
    for (int it = 0; it < 32; ++it) {
        int k0 = it * 32;
        __syncthreads();
        #pragma unroll
        for (int i = 0; i < 2; ++i) {
            int g = i*256 + t;
            int row = g >> 2, seg = g & 3;
            short8 v = *(const short8*)(hb + (size_t)(m0+row)*HIDD + k0 + seg*8);
            *(short8*)(&Ahs[row*40 + seg*8]) = v;
        }
        __syncthreads();
        #pragma unroll
        for (int ct = 0; ct < 11; ++ct) {
            bf16x8 bfr = *(const bf16x8*)(whb + (size_t)(ct*16 + ln15)*HIDD + k0 + q*8);
            #pragma unroll
            for (int rt = 0; rt < 2; ++rt) {
                bf16x8 af = *(const bf16x8*)(&Ahs[(wr + rt*16 + ln15)*40 + q*8]);
                acc[rt][ct] = mfma_bf16(af, bfr, acc[rt][ct]);
            }
        }
    }
    #pragma unroll
    for (int ct = 0; ct < 11; ++ct) {
        int n = ct*16 + ln15;
        float bc = (n < 81) ? bcls[n] : ((n < 162) ? bbox[n-81] : 0.f);
        #pragma unroll
        for (int rt = 0; rt < 2; ++rt)
            #pragma unroll
            for (int r = 0; r < 4; ++r) {
                int row = m0 + wr + rt*16 + q*4 + r;
                float v = acc[rt][ct][r] + bc;
                if (n < 81)       sc[row*NCLS + n] = v;
                else if (n < 162) out[41472 + row*NCLS + (n-81)] = v;
            }
    }
}

__global__ void k_softmax(const float* __restrict__ sc, float* __restrict__ out) {
    __shared__ float v[NCLS];
    __shared__ float red[2];
    int m = blockIdx.x, t = threadIdx.x;
    if (t < NCLS) v[t] = sc[m*NCLS + t];
    __syncthreads();
    if (t == 0) {
        float mx = -3.0e38f;
        for (int i = 0; i < NCLS; ++i) mx = fmaxf(mx, v[i]);
        red[0] = mx;
    }
    __syncthreads();
    if (t < NCLS) v[t] = expf(v[t] - red[0]);
    __syncthreads();
    if (t == 0) {
        float sm = 0.f;
        for (int i = 0; i < NCLS; ++i) sm += v[i];
        red[1] = sm;
    }
    __syncthreads();
    if (t < NCLS) out[m*NCLS + t] = v[t] / red[1];
}

__global__ void k_mask(const float* __restrict__ zmean, const float* __restrict__ wm,
                       const float* __restrict__ bm, float* __restrict__ out) {
    __shared__ float zs[256];
    int m = blockIdx.x, t = threadIdx.x;
    #pragma unroll
    for (int i = 0; i < 2; ++i) zs[t + i*128] = zmean[m*256 + t + i*128];
    __syncthreads();
    if (t < NCLS) {
        float a = bm[t];
        #pragma unroll 4
        for (int k = 0; k < 256; ++k) a += zs[k] * wm[k*NCLS + t];
        out[82944 + m*NCLS + t] = 1.0f / (1.0f + expf(-a));
    }
}

// ---------------------------------------------------------------------------
extern "C" void kernel_launch(void* const* d_in, const int* in_sizes, int n_in,
                              void* d_out, int out_size, void* d_ws, size_t ws_size,
                              hipStream_t stream) {
    (void)in_sizes; (void)n_in; (void)out_size; (void)ws_size;
    const float* p2    = (const float*)d_in[0];
    const float* p3    = (const float*)d_in[1];
    const float* p4    = (const float*)d_in[2];
    const float* p5    = (const float*)d_in[3];
    const float* boxes = (const float*)d_in[4];
    const int*   bidx  = (const int*)d_in[5];
    const float* wfc1  = (const float*)d_in[6];
    const float* bfc1  = (const float*)d_in[7];
    const float* wcls  = (const float*)d_in[8];
    const float* bcls  = (const float*)d_in[9];
    const float* wbox  = (const float*)d_in[10];
    const float* bbox  = (const float*)d_in[11];
    const float* wconv = (const float*)d_in[12];
    const float* bconv = (const float*)d_in[13];
    const float* wmfc  = (const float*)d_in[14];
    const float* bmfc  = (const float*)d_in[15];
    const int*   imh   = (const int*)d_in[16];
    const int*   imw   = (const int*)d_in[17];

    // Workspace layout (total 346,816,512 B — same envelope as round-2 known-good):
    //   [0, 205520896)          fpt0..3 (108.8 MB, dead after k_roi) / packedB (after)
    //   [205520896, 239075328)  partials 33.5 MB
    //   [239075328, 240123904)  hb (bf16 h) 1 MB
    //   [240123904, 240648192)  zmean 512 KB
    //   [240648192, 243007488)  wconvb 2.36 MB
    //   [243007488, 243367936)  whb 360 KB
    //   [243367936, 243533824)  sc 166 KB
    //   [244056064, 346816512)  pooled 102.76 MB
    char* ws = (char*)d_ws;
    unsigned short* fpt0     = (unsigned short*)(ws);
    unsigned short* fpt1     = (unsigned short*)(ws + 81920000ull);
    unsigned short* fpt2     = (unsigned short*)(ws + 102400000ull);
    unsigned short* fpt3     = (unsigned short*)(ws + 107520000ull);
    unsigned short* packedB  = (unsigned short*)(ws);
    float*          partials = (float*)(ws + 205520896ull);
    unsigned short* hb       = (unsigned short*)(ws + 239075328ull);
    float*          zmean    = (float*)(ws + 240123904ull);
    unsigned short* wconvb   = (unsigned short*)(ws + 240648192ull);
    unsigned short* whb      = (unsigned short*)(ws + 243007488ull);
    float*          sc       = (float*)(ws + 243367936ull);
    unsigned short* pooled   = (unsigned short*)(ws + 244056064ull);
    float*          out      = (float*)d_out;

    hipLaunchKernelGGL(k_tr, dim3(832, 16), dim3(256), 0, stream,
                       p2, p3, p4, p5, fpt0, fpt1, fpt2, fpt3);
    hipLaunchKernelGGL(k_roi, dim3(512), dim3(256), 0, stream,
                       fpt0, fpt1, fpt2, fpt3, boxes, bidx, imh, imw, pooled);
    hipLaunchKernelGGL(k_pack_wfc1,  dim3(50176), dim3(256), 0, stream, wfc1, packedB);
    hipLaunchKernelGGL(k_pack_wconv, dim3(5120),  dim3(256), 0, stream, wconv, wconvb, zmean);
    hipLaunchKernelGGL(k_pack_whead, dim3(704),   dim3(256), 0, stream, wcls, wbox, whb);
    hipLaunchKernelGGL(k_conv, dim3(2, 512), dim3(256), 0, stream, pooled, wconvb, bconv, zmean);
    hipLaunchKernelGGL(k_fc1,  dim3(8, 2, 16), dim3(256), 0, stream, pooled, packedB, partials);
    hipLaunchKernelGGL(k_fc1_red, dim3(2048), dim3(256), 0, stream, partials, bfc1, hb);
    hipLaunchKernelGGL(k_head, dim3(4), dim3(256), 0, stream, hb, whb, bcls, bbox, sc, out);
    hipLaunchKernelGGL(k_softmax, dim3(512), dim3(128), 0, stream, sc, out);
    hipLaunchKernelGGL(k_mask, dim3(512), dim3(128), 0, stream, zmean, wmfc, bmfc, out);
}